// Round 4
// baseline (6603.702 us; speedup 1.0000x reference)
//
#include <hip/hip_runtime.h>
#include <math.h>

#define DM 512
#define NSEQ 1025
#define BATCH 4

#define LD4(p) (*(const float4*)(p))

__device__ __forceinline__ float wave_sum(float v) {
#pragma unroll
  for (int off = 32; off > 0; off >>= 1) v += __shfl_xor(v, off, 64);
  return v;
}
__device__ __forceinline__ float wave_max(float v) {
#pragma unroll
  for (int off = 32; off > 0; off >>= 1) v = fmaxf(v, __shfl_xor(v, off, 64));
  return v;
}
__device__ __forceinline__ float4 f4fma(float s, float4 a, float4 acc) {
  acc.x = fmaf(s, a.x, acc.x); acc.y = fmaf(s, a.y, acc.y);
  acc.z = fmaf(s, a.z, acc.z); acc.w = fmaf(s, a.w, acc.w);
  return acc;
}
__device__ __forceinline__ float4 f4add(float4 a, float4 b) {
  a.x += b.x; a.y += b.y; a.z += b.z; a.w += b.w; return a;
}
__device__ __forceinline__ float gelu_f(float x) {
  return 0.5f * x * (1.0f + erff(x * 0.70710678118654752f));
}

// ---------------- rel-position bias table: relvals[r] for rel = r-1024 -------
__global__ void relbias_k(const float* __restrict__ rel_emb, float* __restrict__ rel) {
  int r = blockIdx.x * 256 + threadIdx.x;
  if (r >= 2049) return;
  int relpos = r - 1024;
  int so = (relpos < 0) ? 16 : 0;
  int dist = (relpos < 0) ? -relpos : relpos;
  int bucket;
  if (dist < 16) {
    bucket = dist;
  } else {
    float large = fminf((float)dist, 128.f);            // already >= 16
    float lr = (float)2.0794415416798357;               // math.log(8 + 1e-8), f32-cast
    float lb = logf(large * (1.f / 16.f) + 1e-8f) / lr * 15.f;
    bucket = (int)lb + 16;
  }
  bucket += so;
  bucket = bucket < 0 ? 0 : (bucket > 31 ? 31 : bucket);
  rel[r] = rel_emb[bucket];
}

// ---------------- small weight prep: vecbuf + CLS rows of x ------------------
// vecbuf layout (floats): vp[512] @0, Mc[3][512] @512, Mo @2048, Ms @3584, cvec @5120
__global__ void prepvec_k(const float* __restrict__ plddt_w, const float* __restrict__ plddt_b,
                          const float* __restrict__ cent_w, const float* __restrict__ cent_b,
                          const float* __restrict__ orient_w, const float* __restrict__ orient_b,
                          const float* __restrict__ sc_w, const float* __restrict__ sc_b,
                          const float* __restrict__ input_proj_b,
                          const float* __restrict__ fusion_w, const float* __restrict__ fusion_b,
                          const float* __restrict__ cls, float* __restrict__ vecb,
                          float* __restrict__ x) {
  int n = blockIdx.x * 256 + threadIdx.x;
  if (n >= 512) return;
  float vp = 0.f, cv = 0.f;
  float mc[3] = {0.f, 0.f, 0.f}, mo[3] = {0.f, 0.f, 0.f}, ms[3] = {0.f, 0.f, 0.f};
  for (int m = 0; m < 512; ++m) {
    float f0 = fusion_w[(size_t)m * 512 + n];
    float f1 = fusion_w[(size_t)(512 + m) * 512 + n];
    float f2 = fusion_w[(size_t)(1024 + m) * 512 + n];
    float f3 = fusion_w[(size_t)(1536 + m) * 512 + n];
    float f4 = fusion_w[(size_t)(2048 + m) * 512 + n];
    vp = fmaf(plddt_w[m], f1, vp);
    cv = fmaf(input_proj_b[m], f0, cv);
    cv = fmaf(plddt_b[m], f1, cv);
    cv = fmaf(cent_b[m], f2, cv);
    cv = fmaf(orient_b[m], f3, cv);
    cv = fmaf(sc_b[m], f4, cv);
#pragma unroll
    for (int c = 0; c < 3; ++c) {
      mc[c] = fmaf(cent_w[c * 512 + m], f2, mc[c]);
      mo[c] = fmaf(orient_w[c * 512 + m], f3, mo[c]);
      ms[c] = fmaf(sc_w[c * 512 + m], f4, ms[c]);
    }
  }
  cv += fusion_b[n];
  vecb[n] = vp;
#pragma unroll
  for (int c = 0; c < 3; ++c) {
    vecb[512 + c * 512 + n] = mc[c];
    vecb[2048 + c * 512 + n] = mo[c];
    vecb[3584 + c * 512 + n] = ms[c];
  }
  vecb[5120 + n] = cv;
  float cl = cls[n];
  for (int b = 0; b < 4; ++b) x[((size_t)b * NSEQ) * DM + n] = cl;
}

// ---------------- generic fp32 GEMM: out = A[M,K] @ W[K,N] (+bias)(+gelu/res)
// EPI: 0 = (+bias), 1 = gelu(+bias), 2 = (+bias)(+res).  Requires N%64==0, K%16==0.
template <int EPI>
__global__ __launch_bounds__(256) void gemm_k(const float* __restrict__ A,
                                              const float* __restrict__ W,
                                              const float* __restrict__ bias,
                                              const float* __restrict__ res,
                                              float* __restrict__ out, int M, int N, int K) {
  __shared__ float As[16][72];
  __shared__ float Bs[16][72];
  const int tid = threadIdx.x;
  const int tx = tid & 15, ty = tid >> 4;
  const int bm = blockIdx.y * 64, bn = blockIdx.x * 64;
  const int arow = bm + (tid >> 2);
  const int akq = (tid & 3) * 4;
  const int brow = tid >> 4;
  const int bcol = bn + tx * 4;
  float acc[4][4] = {};
  for (int kt = 0; kt < K; kt += 16) {
    float4 av = make_float4(0.f, 0.f, 0.f, 0.f);
    if (arow < M) av = LD4(A + (size_t)arow * K + kt + akq);
    float4 bv = LD4(W + (size_t)(kt + brow) * N + bcol);
    As[akq + 0][tid >> 2] = av.x;
    As[akq + 1][tid >> 2] = av.y;
    As[akq + 2][tid >> 2] = av.z;
    As[akq + 3][tid >> 2] = av.w;
    *(float4*)(&Bs[brow][tx * 4]) = bv;
    __syncthreads();
#pragma unroll
    for (int kk = 0; kk < 16; ++kk) {
      float4 a4 = LD4(&As[kk][ty * 4]);
      float4 b4 = LD4(&Bs[kk][tx * 4]);
      float aa[4] = {a4.x, a4.y, a4.z, a4.w};
      float bb[4] = {b4.x, b4.y, b4.z, b4.w};
#pragma unroll
      for (int i = 0; i < 4; ++i)
#pragma unroll
        for (int j = 0; j < 4; ++j) acc[i][j] = fmaf(aa[i], bb[j], acc[i][j]);
    }
    __syncthreads();
  }
  const int gn = bn + tx * 4;
  float4 bb4 = make_float4(0.f, 0.f, 0.f, 0.f);
  if (bias) bb4 = LD4(bias + gn);
#pragma unroll
  for (int ii = 0; ii < 4; ++ii) {
    int gm = bm + ty * 4 + ii;
    if (gm >= M) continue;
    float4 v = make_float4(acc[ii][0], acc[ii][1], acc[ii][2], acc[ii][3]);
    v = f4add(v, bb4);
    if (EPI == 1) {
      v.x = gelu_f(v.x); v.y = gelu_f(v.y); v.z = gelu_f(v.z); v.w = gelu_f(v.w);
    }
    if (EPI == 2) v = f4add(v, LD4(res + (size_t)gm * N + gn));
    *(float4*)(out + (size_t)gm * N + gn) = v;
  }
}

// ---------------- embedding GEMM: x[b,1+i,:] = seq@Wc + small-feature epilogue
__global__ __launch_bounds__(256) void gemm_embed_k(const float* __restrict__ A,
                                                    const float* __restrict__ W,
                                                    const float* __restrict__ vecb,
                                                    const float* __restrict__ plddt,
                                                    const float* __restrict__ cent,
                                                    const float* __restrict__ orient,
                                                    const float* __restrict__ scv,
                                                    const float* __restrict__ pos_enc,
                                                    float* __restrict__ x) {
  const int K = 2560, N = 512;  // M = 4096
  __shared__ float As[16][72];
  __shared__ float Bs[16][72];
  const int tid = threadIdx.x;
  const int tx = tid & 15, ty = tid >> 4;
  const int bm = blockIdx.y * 64, bn = blockIdx.x * 64;
  const int arow = bm + (tid >> 2);
  const int akq = (tid & 3) * 4;
  const int brow = tid >> 4;
  const int bcol = bn + tx * 4;
  float acc[4][4] = {};
  for (int kt = 0; kt < K; kt += 16) {
    float4 av = LD4(A + (size_t)arow * K + kt + akq);
    float4 bv = LD4(W + (size_t)(kt + brow) * N + bcol);
    As[akq + 0][tid >> 2] = av.x;
    As[akq + 1][tid >> 2] = av.y;
    As[akq + 2][tid >> 2] = av.z;
    As[akq + 3][tid >> 2] = av.w;
    *(float4*)(&Bs[brow][tx * 4]) = bv;
    __syncthreads();
#pragma unroll
    for (int kk = 0; kk < 16; ++kk) {
      float4 a4 = LD4(&As[kk][ty * 4]);
      float4 b4 = LD4(&Bs[kk][tx * 4]);
      float aa[4] = {a4.x, a4.y, a4.z, a4.w};
      float bb[4] = {b4.x, b4.y, b4.z, b4.w};
#pragma unroll
      for (int i = 0; i < 4; ++i)
#pragma unroll
        for (int j = 0; j < 4; ++j) acc[i][j] = fmaf(aa[i], bb[j], acc[i][j]);
    }
    __syncthreads();
  }
  const int gn = bn + tx * 4;
  float4 vp4 = LD4(vecb + gn);
  float4 mc0 = LD4(vecb + 512 + gn), mc1 = LD4(vecb + 1024 + gn), mc2 = LD4(vecb + 1536 + gn);
  float4 mo0 = LD4(vecb + 2048 + gn), mo1 = LD4(vecb + 2560 + gn), mo2 = LD4(vecb + 3072 + gn);
  float4 ms0 = LD4(vecb + 3584 + gn), ms1 = LD4(vecb + 4096 + gn), ms2 = LD4(vecb + 4608 + gn);
  float4 cv4 = LD4(vecb + 5120 + gn);
#pragma unroll
  for (int ii = 0; ii < 4; ++ii) {
    int gm = bm + ty * 4 + ii;
    int b = gm >> 10, i = gm & 1023;
    float4 v = make_float4(acc[ii][0], acc[ii][1], acc[ii][2], acc[ii][3]);
    v = f4add(v, cv4);
    v = f4fma(plddt[gm], vp4, v);
    const float* cp = cent + 3 * (size_t)gm;
    v = f4fma(cp[0], mc0, v); v = f4fma(cp[1], mc1, v); v = f4fma(cp[2], mc2, v);
    const float* op2 = orient + 3 * (size_t)gm;
    v = f4fma(op2[0], mo0, v); v = f4fma(op2[1], mo1, v); v = f4fma(op2[2], mo2, v);
    const float* sp = scv + 3 * (size_t)gm;
    v = f4fma(sp[0], ms0, v); v = f4fma(sp[1], ms1, v); v = f4fma(sp[2], ms2, v);
    v = f4add(v, LD4(pos_enc + (size_t)i * 512 + gn));
    *(float4*)(x + ((size_t)(b * NSEQ + 1 + i)) * DM + gn) = v;
  }
}

// ---------------- pair bias: bias[b,ii,jj] -----------------------------------
__global__ __launch_bounds__(256) void pairbias_k(const float* __restrict__ ed,
                                                  const float* __restrict__ pae,
                                                  const float* __restrict__ ev,
                                                  const float* __restrict__ pair_w,
                                                  const float* __restrict__ pair_b,
                                                  const float* __restrict__ rel,
                                                  float* __restrict__ biasb) {
  int rowid = blockIdx.x;
  int b = rowid / NSEQ, ii = rowid % NSEQ;
  float w0 = pair_w[0], w1 = pair_w[1], w2 = pair_w[2], w3 = pair_w[3], w4 = pair_w[4];
  float pb = pair_b[0];
  float* orow = biasb + ((size_t)b * NSEQ + ii) * NSEQ;
  for (int jj = threadIdx.x; jj < NSEQ; jj += 256) {
    float v = rel[jj - ii + 1024];
    if (ii > 0 && jj > 0) {
      size_t e = ((size_t)b * 1024 + (ii - 1)) * 1024 + (jj - 1);
      v += ed[e] * w0 + pae[e] * w1 + ev[3 * e] * w2 + ev[3 * e + 1] * w3 + ev[3 * e + 2] * w4 + pb;
    }
    orow[jj] = v;
  }
}

// ---------------- LayerNorm over last dim (512) ------------------------------
__global__ __launch_bounds__(64) void ln_k(const float* __restrict__ in, float* __restrict__ outp,
                                           const float* __restrict__ g, const float* __restrict__ bt,
                                           int nrows, int instride, int outstride) {
  int row = blockIdx.x;
  if (row >= nrows) return;
  int lane = threadIdx.x;
  const float* p = in + (size_t)row * instride;
  float4 a = LD4(p + lane * 4);
  float4 c = LD4(p + 256 + lane * 4);
  float s = a.x + a.y + a.z + a.w + c.x + c.y + c.z + c.w;
  s = wave_sum(s);
  float m = s * (1.f / 512.f);
  float dx[8] = {a.x - m, a.y - m, a.z - m, a.w - m, c.x - m, c.y - m, c.z - m, c.w - m};
  float q = 0.f;
#pragma unroll
  for (int i = 0; i < 8; ++i) q = fmaf(dx[i], dx[i], q);
  q = wave_sum(q);
  float rinv = 1.f / sqrtf(q * (1.f / 512.f) + 1e-5f);
  float4 g0 = LD4(g + lane * 4), g1 = LD4(g + 256 + lane * 4);
  float4 b0 = LD4(bt + lane * 4), b1 = LD4(bt + 256 + lane * 4);
  float4 o0 = make_float4(dx[0] * rinv * g0.x + b0.x, dx[1] * rinv * g0.y + b0.y,
                          dx[2] * rinv * g0.z + b0.z, dx[3] * rinv * g0.w + b0.w);
  float4 o1 = make_float4(dx[4] * rinv * g1.x + b1.x, dx[5] * rinv * g1.y + b1.y,
                          dx[6] * rinv * g1.z + b1.z, dx[7] * rinv * g1.w + b1.w);
  *(float4*)(outp + (size_t)row * outstride + lane * 4) = o0;
  *(float4*)(outp + (size_t)row * outstride + 256 + lane * 4) = o1;
}

// ---------------- fused flash attention --------------------------------------
// grid (17, 8, 4), block 256 (4 waves x 16 rows). qkv row: [q(512) k(512) v(512)]
// LDS: Kt[64][65] (padded: column reads), Vt[64][64], Qt[64][64].
// P (per-wave [64 j][16 r], stride 16) aliases Kt: 4*64*16 = 4096 floats <= 4160.
__global__ __launch_bounds__(256) void attn_k(const float* __restrict__ qkv,
                                              const float* __restrict__ bias,
                                              float* __restrict__ o) {
  __shared__ float Kt[64][65];
  __shared__ float Vt[64][64];
  __shared__ float Qt[64][64];   // [d][tile-row]
  float* Pt = &Kt[0][0];         // alias: index w*1024 + j*16 + r  (4096 <= 64*65=4160)
  const int tid = threadIdx.x;
  const int lane = tid & 63;
  const int w = tid >> 6;
  const int h = blockIdx.y, b = blockIdx.z;
  const int i0 = blockIdx.x * 64;
  const float* qk = qkv + (size_t)b * NSEQ * 1536;
#pragma unroll
  for (int rr = 0; rr < 16; ++rr) {
    int r = w + rr * 4;   // rows r ≡ w (mod 4): all 64 rows covered across 4 waves
    int ig = i0 + r;
    Qt[lane][r] = (ig < NSEQ) ? qk[(size_t)ig * 1536 + h * 64 + lane] : 0.f;
  }
  float m_r[16], l_r[16], o_acc[16];
#pragma unroll
  for (int r = 0; r < 16; ++r) { m_r[r] = -1e30f; l_r[r] = 0.f; o_acc[r] = 0.f; }
  for (int j0 = 0; j0 < NSEQ; j0 += 64) {
    __syncthreads();   // previous iter's PV (Vt, P-in-Kt) fully consumed
#pragma unroll
    for (int rr = 0; rr < 16; ++rr) {
      int r = w + rr * 4;
      int jg = j0 + r;
      float kv = 0.f, vv = 0.f;
      if (jg < NSEQ) {
        kv = qk[(size_t)jg * 1536 + 512 + h * 64 + lane];
        vv = qk[(size_t)jg * 1536 + 1024 + h * 64 + lane];
      }
      Kt[r][lane] = kv;
      Vt[r][lane] = vv;
    }
    __syncthreads();
    float s[16];
#pragma unroll
    for (int r = 0; r < 16; ++r) s[r] = 0.f;
#pragma unroll 4
    for (int d = 0; d < 64; ++d) {
      float kvd = Kt[lane][d];           // lane stride 65 -> conflict-free
#pragma unroll
      for (int q4 = 0; q4 < 4; ++q4) {
        float4 qv = LD4(&Qt[d][w * 16 + q4 * 4]);  // wave-uniform broadcast
        s[q4 * 4 + 0] = fmaf(qv.x, kvd, s[q4 * 4 + 0]);
        s[q4 * 4 + 1] = fmaf(qv.y, kvd, s[q4 * 4 + 1]);
        s[q4 * 4 + 2] = fmaf(qv.z, kvd, s[q4 * 4 + 2]);
        s[q4 * 4 + 3] = fmaf(qv.w, kvd, s[q4 * 4 + 3]);
      }
    }
    __syncthreads();   // everyone done reading Kt -> safe to overwrite with P
    int jg = j0 + lane;
    bool jv = jg < NSEQ;
#pragma unroll
    for (int q4 = 0; q4 < 4; ++q4) {
      float pv[4];
#pragma unroll
      for (int k = 0; k < 4; ++k) {
        int r = q4 * 4 + k;
        int ig = i0 + w * 16 + r;
        float sv = s[r] * 0.125f;
        if (jv && ig < NSEQ) sv += bias[((size_t)b * NSEQ + ig) * NSEQ + jg];
        if (!jv) sv = -1e30f;
        float mt = wave_max(sv);
        float mnew = fmaxf(m_r[r], mt);
        float fct = __expf(m_r[r] - mnew);
        float p = __expf(sv - mnew);
        float ls = wave_sum(p);
        l_r[r] = l_r[r] * fct + ls;
        m_r[r] = mnew;
        o_acc[r] *= fct;
        pv[k] = p;
      }
      // intra-wave only: write own wave's P region (no barrier needed before PV)
      *(float4*)(&Pt[w * 1024 + lane * 16 + q4 * 4]) = make_float4(pv[0], pv[1], pv[2], pv[3]);
    }
#pragma unroll 4
    for (int j = 0; j < 64; ++j) {
      float vv = Vt[j][lane];            // lane stride 1 -> conflict-free
#pragma unroll
      for (int q4 = 0; q4 < 4; ++q4) {
        float4 p4 = LD4(&Pt[w * 1024 + j * 16 + q4 * 4]);  // wave-uniform broadcast
        o_acc[q4 * 4 + 0] = fmaf(p4.x, vv, o_acc[q4 * 4 + 0]);
        o_acc[q4 * 4 + 1] = fmaf(p4.y, vv, o_acc[q4 * 4 + 1]);
        o_acc[q4 * 4 + 2] = fmaf(p4.z, vv, o_acc[q4 * 4 + 2]);
        o_acc[q4 * 4 + 3] = fmaf(p4.w, vv, o_acc[q4 * 4 + 3]);
      }
    }
  }
#pragma unroll
  for (int r = 0; r < 16; ++r) {
    int ig = i0 + w * 16 + r;
    if (ig < NSEQ) o[((size_t)b * NSEQ + ig) * DM + h * 64 + lane] = o_acc[r] / l_r[r];
  }
}

// ---------------- head: out[b,:] = x0[b]@head_w + head_b ---------------------
__global__ __launch_bounds__(256) void head_k(const float* __restrict__ x0,
                                              const float* __restrict__ head_w,
                                              const float* __restrict__ head_b,
                                              float* __restrict__ outp) {
  __shared__ float xs[512];
  int b = blockIdx.y;
  for (int c = threadIdx.x; c < 512; c += 256) xs[c] = x0[b * 512 + c];
  __syncthreads();
  int j = blockIdx.x * 256 + threadIdx.x;
  if (j >= 4273) return;
  float acc = head_b[j];
  for (int k = 0; k < 512; ++k) acc = fmaf(xs[k], head_w[(size_t)k * 4273 + j], acc);
  outp[(size_t)b * 4273 + j] = acc;
}

extern "C" void kernel_launch(void* const* d_in, const int* in_sizes, int n_in,
                              void* d_out, int out_size, void* d_ws, size_t ws_size,
                              hipStream_t stream) {
  const float* seq_embed = (const float*)d_in[0];
  const float* pae = (const float*)d_in[1];
  const float* plddt = (const float*)d_in[2];
  const float* centroid = (const float*)d_in[3];
  const float* orientv = (const float*)d_in[4];
  const float* scv = (const float*)d_in[5];
  const float* eucl = (const float*)d_in[6];
  const float* edgev = (const float*)d_in[7];
  const float* input_proj_w = (const float*)d_in[8];
  const float* input_proj_b = (const float*)d_in[9];
  const float* plddt_w = (const float*)d_in[10];
  const float* plddt_b = (const float*)d_in[11];
  const float* cent_w = (const float*)d_in[12];
  const float* cent_b = (const float*)d_in[13];
  const float* orient_w = (const float*)d_in[14];
  const float* orient_b = (const float*)d_in[15];
  const float* sc_w = (const float*)d_in[16];
  const float* sc_b = (const float*)d_in[17];
  const float* fusion_w = (const float*)d_in[18];
  const float* fusion_b = (const float*)d_in[19];
  const float* pair_w = (const float*)d_in[20];
  const float* pair_b = (const float*)d_in[21];
  const float* pos_enc = (const float*)d_in[22];
  const float* cls_token = (const float*)d_in[23];
  const float* rel_emb = (const float*)d_in[24];
  const float* ln1_g = (const float*)d_in[25];
  const float* ln1_b = (const float*)d_in[26];
  const float* ln2_g = (const float*)d_in[27];
  const float* ln2_b = (const float*)d_in[28];
  const float* in_proj_w = (const float*)d_in[29];
  const float* in_proj_b = (const float*)d_in[30];
  const float* out_proj_w = (const float*)d_in[31];
  const float* out_proj_b = (const float*)d_in[32];
  const float* ff1_w = (const float*)d_in[33];
  const float* ff1_b = (const float*)d_in[34];
  const float* ff2_w = (const float*)d_in[35];
  const float* ff2_b = (const float*)d_in[36];
  const float* norm_g = (const float*)d_in[37];
  const float* norm_b = (const float*)d_in[38];
  const float* head_w = (const float*)d_in[39];
  const float* head_b = (const float*)d_in[40];
  float* outp = (float*)d_out;

  char* ws = (char*)d_ws;
  size_t off = 0;
  auto alloc = [&](size_t bytes) -> float* {
    float* p = (float*)(ws + off);
    off = (off + bytes + 255) & ~(size_t)255;
    return p;
  };
  float* Wc = alloc((size_t)2560 * 512 * 4);
  float* vecb = alloc(5632 * 4);
  float* rel = alloc(2049 * 4);
  float* x = alloc((size_t)BATCH * NSEQ * DM * 4);
  float* biasb = alloc((size_t)BATCH * NSEQ * NSEQ * 4);
  float* z = alloc((size_t)BATCH * NSEQ * DM * 4);
  float* qkvb = alloc((size_t)BATCH * NSEQ * 1536 * 4);
  float* attb = alloc((size_t)BATCH * NSEQ * DM * 4);
  float* hbuf = alloc((size_t)BATCH * NSEQ * 1024 * 4);
  float* x0 = alloc(4 * 512 * 4);
  (void)ws_size; (void)in_sizes; (void)n_in; (void)out_size;

  relbias_k<<<9, 256, 0, stream>>>(rel_emb, rel);
  prepvec_k<<<2, 256, 0, stream>>>(plddt_w, plddt_b, cent_w, cent_b, orient_w, orient_b,
                                   sc_w, sc_b, input_proj_b, fusion_w, fusion_b, cls_token,
                                   vecb, x);
  // Wc = input_proj_w @ fusion_w[0:512,:]
  gemm_k<0><<<dim3(8, 40), 256, 0, stream>>>(input_proj_w, fusion_w, nullptr, nullptr, Wc,
                                             2560, 512, 512);
  gemm_embed_k<<<dim3(8, 64), 256, 0, stream>>>(seq_embed, Wc, vecb, plddt, centroid, orientv,
                                                scv, pos_enc, x);
  pairbias_k<<<BATCH * NSEQ, 256, 0, stream>>>(eucl, pae, edgev, pair_w, pair_b, rel, biasb);

  for (int l = 0; l < 6; ++l) {
    ln_k<<<4100, 64, 0, stream>>>(x, z, ln1_g + l * 512, ln1_b + l * 512, 4100, 512, 512);
    gemm_k<0><<<dim3(24, 65), 256, 0, stream>>>(z, in_proj_w + (size_t)l * 512 * 1536,
                                                in_proj_b + (size_t)l * 1536, nullptr, qkvb,
                                                4100, 1536, 512);
    attn_k<<<dim3(17, 8, 4), 256, 0, stream>>>(qkvb, biasb, attb);
    gemm_k<2><<<dim3(8, 65), 256, 0, stream>>>(attb, out_proj_w + (size_t)l * 512 * 512,
                                               out_proj_b + (size_t)l * 512, x, x, 4100, 512, 512);
    ln_k<<<4100, 64, 0, stream>>>(x, z, ln2_g + l * 512, ln2_b + l * 512, 4100, 512, 512);
    gemm_k<1><<<dim3(16, 65), 256, 0, stream>>>(z, ff1_w + (size_t)l * 512 * 1024,
                                                ff1_b + (size_t)l * 1024, nullptr, hbuf,
                                                4100, 1024, 512);
    gemm_k<2><<<dim3(8, 65), 256, 0, stream>>>(hbuf, ff2_w + (size_t)l * 1024 * 512,
                                               ff2_b + (size_t)l * 512, x, x, 4100, 512, 1024);
  }
  ln_k<<<4, 64, 0, stream>>>(x, x0, norm_g, norm_b, 4, NSEQ * DM, 512);
  head_k<<<dim3(17, 4), 256, 0, stream>>>(x0, head_w, head_b, outp);
}

// Round 5
// 5630.618 us; speedup vs baseline: 1.1728x; 1.1728x over previous
//
#include <hip/hip_runtime.h>
#include <math.h>

#define DM 512
#define NSEQ 1025
#define BATCH 4

#define LD4(p) (*(const float4*)(p))

typedef __attribute__((ext_vector_type(8))) short bf16x8;
typedef __attribute__((ext_vector_type(4))) float f32x4;

__device__ __forceinline__ float wave_sum(float v) {
#pragma unroll
  for (int off = 32; off > 0; off >>= 1) v += __shfl_xor(v, off, 64);
  return v;
}
__device__ __forceinline__ float wave_max(float v) {
#pragma unroll
  for (int off = 32; off > 0; off >>= 1) v = fmaxf(v, __shfl_xor(v, off, 64));
  return v;
}
__device__ __forceinline__ float4 f4fma(float s, float4 a, float4 acc) {
  acc.x = fmaf(s, a.x, acc.x); acc.y = fmaf(s, a.y, acc.y);
  acc.z = fmaf(s, a.z, acc.z); acc.w = fmaf(s, a.w, acc.w);
  return acc;
}
__device__ __forceinline__ float4 f4add(float4 a, float4 b) {
  a.x += b.x; a.y += b.y; a.z += b.z; a.w += b.w; return a;
}
__device__ __forceinline__ float gelu_f(float x) {
  return 0.5f * x * (1.0f + erff(x * 0.70710678118654752f));
}
__device__ __forceinline__ unsigned short f2bf(float f) {
  unsigned u = __float_as_uint(f);
  u += 0x7FFFu + ((u >> 16) & 1u);
  return (unsigned short)(u >> 16);
}

// ---------------- rel-position bias table: relvals[r] for rel = r-1024 -------
__global__ void relbias_k(const float* __restrict__ rel_emb, float* __restrict__ rel) {
  int r = blockIdx.x * 256 + threadIdx.x;
  if (r >= 2049) return;
  int relpos = r - 1024;
  int so = (relpos < 0) ? 16 : 0;
  int dist = (relpos < 0) ? -relpos : relpos;
  int bucket;
  if (dist < 16) {
    bucket = dist;
  } else {
    float large = fminf((float)dist, 128.f);
    float lr = (float)2.0794415416798357;
    float lb = logf(large * (1.f / 16.f) + 1e-8f) / lr * 15.f;
    bucket = (int)lb + 16;
  }
  bucket += so;
  bucket = bucket < 0 ? 0 : (bucket > 31 ? 31 : bucket);
  rel[r] = rel_emb[bucket];
}

// ---------------- small weight prep: vecbuf + CLS rows of x ------------------
__global__ void prepvec_k(const float* __restrict__ plddt_w, const float* __restrict__ plddt_b,
                          const float* __restrict__ cent_w, const float* __restrict__ cent_b,
                          const float* __restrict__ orient_w, const float* __restrict__ orient_b,
                          const float* __restrict__ sc_w, const float* __restrict__ sc_b,
                          const float* __restrict__ input_proj_b,
                          const float* __restrict__ fusion_w, const float* __restrict__ fusion_b,
                          const float* __restrict__ cls, float* __restrict__ vecb,
                          float* __restrict__ x) {
  int n = blockIdx.x * 256 + threadIdx.x;
  if (n >= 512) return;
  float vp = 0.f, cv = 0.f;
  float mc[3] = {0.f, 0.f, 0.f}, mo[3] = {0.f, 0.f, 0.f}, ms[3] = {0.f, 0.f, 0.f};
  for (int m = 0; m < 512; ++m) {
    float f0 = fusion_w[(size_t)m * 512 + n];
    float f1 = fusion_w[(size_t)(512 + m) * 512 + n];
    float f2 = fusion_w[(size_t)(1024 + m) * 512 + n];
    float f3 = fusion_w[(size_t)(1536 + m) * 512 + n];
    float f4 = fusion_w[(size_t)(2048 + m) * 512 + n];
    vp = fmaf(plddt_w[m], f1, vp);
    cv = fmaf(input_proj_b[m], f0, cv);
    cv = fmaf(plddt_b[m], f1, cv);
    cv = fmaf(cent_b[m], f2, cv);
    cv = fmaf(orient_b[m], f3, cv);
    cv = fmaf(sc_b[m], f4, cv);
#pragma unroll
    for (int c = 0; c < 3; ++c) {
      mc[c] = fmaf(cent_w[c * 512 + m], f2, mc[c]);
      mo[c] = fmaf(orient_w[c * 512 + m], f3, mo[c]);
      ms[c] = fmaf(sc_w[c * 512 + m], f4, ms[c]);
    }
  }
  cv += fusion_b[n];
  vecb[n] = vp;
#pragma unroll
  for (int c = 0; c < 3; ++c) {
    vecb[512 + c * 512 + n] = mc[c];
    vecb[2048 + c * 512 + n] = mo[c];
    vecb[3584 + c * 512 + n] = ms[c];
  }
  vecb[5120 + n] = cv;
  float cl = cls[n];
  for (int b = 0; b < 4; ++b) x[((size_t)b * NSEQ) * DM + n] = cl;
}

// ---------------- generic fp32 GEMM (kept for Wc / embed) --------------------
template <int EPI>
__global__ __launch_bounds__(256) void gemm_k(const float* __restrict__ A,
                                              const float* __restrict__ W,
                                              const float* __restrict__ bias,
                                              const float* __restrict__ res,
                                              float* __restrict__ out, int M, int N, int K) {
  __shared__ float As[16][72];
  __shared__ float Bs[16][72];
  const int tid = threadIdx.x;
  const int tx = tid & 15, ty = tid >> 4;
  const int bm = blockIdx.y * 64, bn = blockIdx.x * 64;
  const int arow = bm + (tid >> 2);
  const int akq = (tid & 3) * 4;
  const int brow = tid >> 4;
  const int bcol = bn + tx * 4;
  float acc[4][4] = {};
  for (int kt = 0; kt < K; kt += 16) {
    float4 av = make_float4(0.f, 0.f, 0.f, 0.f);
    if (arow < M) av = LD4(A + (size_t)arow * K + kt + akq);
    float4 bv = LD4(W + (size_t)(kt + brow) * N + bcol);
    As[akq + 0][tid >> 2] = av.x;
    As[akq + 1][tid >> 2] = av.y;
    As[akq + 2][tid >> 2] = av.z;
    As[akq + 3][tid >> 2] = av.w;
    *(float4*)(&Bs[brow][tx * 4]) = bv;
    __syncthreads();
#pragma unroll
    for (int kk = 0; kk < 16; ++kk) {
      float4 a4 = LD4(&As[kk][ty * 4]);
      float4 b4 = LD4(&Bs[kk][tx * 4]);
      float aa[4] = {a4.x, a4.y, a4.z, a4.w};
      float bb[4] = {b4.x, b4.y, b4.z, b4.w};
#pragma unroll
      for (int i = 0; i < 4; ++i)
#pragma unroll
        for (int j = 0; j < 4; ++j) acc[i][j] = fmaf(aa[i], bb[j], acc[i][j]);
    }
    __syncthreads();
  }
  const int gn = bn + tx * 4;
  float4 bb4 = make_float4(0.f, 0.f, 0.f, 0.f);
  if (bias) bb4 = LD4(bias + gn);
#pragma unroll
  for (int ii = 0; ii < 4; ++ii) {
    int gm = bm + ty * 4 + ii;
    if (gm >= M) continue;
    float4 v = make_float4(acc[ii][0], acc[ii][1], acc[ii][2], acc[ii][3]);
    v = f4add(v, bb4);
    if (EPI == 1) {
      v.x = gelu_f(v.x); v.y = gelu_f(v.y); v.z = gelu_f(v.z); v.w = gelu_f(v.w);
    }
    if (EPI == 2) v = f4add(v, LD4(res + (size_t)gm * N + gn));
    *(float4*)(out + (size_t)gm * N + gn) = v;
  }
}

// ---------------- embedding GEMM ---------------------------------------------
__global__ __launch_bounds__(256) void gemm_embed_k(const float* __restrict__ A,
                                                    const float* __restrict__ W,
                                                    const float* __restrict__ vecb,
                                                    const float* __restrict__ plddt,
                                                    const float* __restrict__ cent,
                                                    const float* __restrict__ orient,
                                                    const float* __restrict__ scv,
                                                    const float* __restrict__ pos_enc,
                                                    float* __restrict__ x) {
  const int K = 2560, N = 512;
  __shared__ float As[16][72];
  __shared__ float Bs[16][72];
  const int tid = threadIdx.x;
  const int tx = tid & 15, ty = tid >> 4;
  const int bm = blockIdx.y * 64, bn = blockIdx.x * 64;
  const int arow = bm + (tid >> 2);
  const int akq = (tid & 3) * 4;
  const int brow = tid >> 4;
  const int bcol = bn + tx * 4;
  float acc[4][4] = {};
  for (int kt = 0; kt < K; kt += 16) {
    float4 av = LD4(A + (size_t)arow * K + kt + akq);
    float4 bv = LD4(W + (size_t)(kt + brow) * N + bcol);
    As[akq + 0][tid >> 2] = av.x;
    As[akq + 1][tid >> 2] = av.y;
    As[akq + 2][tid >> 2] = av.z;
    As[akq + 3][tid >> 2] = av.w;
    *(float4*)(&Bs[brow][tx * 4]) = bv;
    __syncthreads();
#pragma unroll
    for (int kk = 0; kk < 16; ++kk) {
      float4 a4 = LD4(&As[kk][ty * 4]);
      float4 b4 = LD4(&Bs[kk][tx * 4]);
      float aa[4] = {a4.x, a4.y, a4.z, a4.w};
      float bb[4] = {b4.x, b4.y, b4.z, b4.w};
#pragma unroll
      for (int i = 0; i < 4; ++i)
#pragma unroll
        for (int j = 0; j < 4; ++j) acc[i][j] = fmaf(aa[i], bb[j], acc[i][j]);
    }
    __syncthreads();
  }
  const int gn = bn + tx * 4;
  float4 vp4 = LD4(vecb + gn);
  float4 mc0 = LD4(vecb + 512 + gn), mc1 = LD4(vecb + 1024 + gn), mc2 = LD4(vecb + 1536 + gn);
  float4 mo0 = LD4(vecb + 2048 + gn), mo1 = LD4(vecb + 2560 + gn), mo2 = LD4(vecb + 3072 + gn);
  float4 ms0 = LD4(vecb + 3584 + gn), ms1 = LD4(vecb + 4096 + gn), ms2 = LD4(vecb + 4608 + gn);
  float4 cv4 = LD4(vecb + 5120 + gn);
#pragma unroll
  for (int ii = 0; ii < 4; ++ii) {
    int gm = bm + ty * 4 + ii;
    int b = gm >> 10, i = gm & 1023;
    float4 v = make_float4(acc[ii][0], acc[ii][1], acc[ii][2], acc[ii][3]);
    v = f4add(v, cv4);
    v = f4fma(plddt[gm], vp4, v);
    const float* cp = cent + 3 * (size_t)gm;
    v = f4fma(cp[0], mc0, v); v = f4fma(cp[1], mc1, v); v = f4fma(cp[2], mc2, v);
    const float* op2 = orient + 3 * (size_t)gm;
    v = f4fma(op2[0], mo0, v); v = f4fma(op2[1], mo1, v); v = f4fma(op2[2], mo2, v);
    const float* sp = scv + 3 * (size_t)gm;
    v = f4fma(sp[0], ms0, v); v = f4fma(sp[1], ms1, v); v = f4fma(sp[2], ms2, v);
    v = f4add(v, LD4(pos_enc + (size_t)i * 512 + gn));
    *(float4*)(x + ((size_t)(b * NSEQ + 1 + i)) * DM + gn) = v;
  }
}

// ---------------- pair bias --------------------------------------------------
__global__ __launch_bounds__(256) void pairbias_k(const float* __restrict__ ed,
                                                  const float* __restrict__ pae,
                                                  const float* __restrict__ ev,
                                                  const float* __restrict__ pair_w,
                                                  const float* __restrict__ pair_b,
                                                  const float* __restrict__ rel,
                                                  float* __restrict__ biasb) {
  int rowid = blockIdx.x;
  int b = rowid / NSEQ, ii = rowid % NSEQ;
  float w0 = pair_w[0], w1 = pair_w[1], w2 = pair_w[2], w3 = pair_w[3], w4 = pair_w[4];
  float pb = pair_b[0];
  float* orow = biasb + ((size_t)b * NSEQ + ii) * NSEQ;
  for (int jj = threadIdx.x; jj < NSEQ; jj += 256) {
    float v = rel[jj - ii + 1024];
    if (ii > 0 && jj > 0) {
      size_t e = ((size_t)b * 1024 + (ii - 1)) * 1024 + (jj - 1);
      v += ed[e] * w0 + pae[e] * w1 + ev[3 * e] * w2 + ev[3 * e + 1] * w3 + ev[3 * e + 2] * w4 + pb;
    }
    orow[jj] = v;
  }
}

// ---------------- LayerNorm over last dim (512); optional bf16 output --------
template <bool BF16OUT>
__global__ __launch_bounds__(64) void ln_k(const float* __restrict__ in, void* __restrict__ outp,
                                           const float* __restrict__ g, const float* __restrict__ bt,
                                           int nrows, int instride, int outstride) {
  int row = blockIdx.x;
  if (row >= nrows) return;
  int lane = threadIdx.x;
  const float* p = in + (size_t)row * instride;
  float4 a = LD4(p + lane * 4);
  float4 c = LD4(p + 256 + lane * 4);
  float s = a.x + a.y + a.z + a.w + c.x + c.y + c.z + c.w;
  s = wave_sum(s);
  float m = s * (1.f / 512.f);
  float dx[8] = {a.x - m, a.y - m, a.z - m, a.w - m, c.x - m, c.y - m, c.z - m, c.w - m};
  float q = 0.f;
#pragma unroll
  for (int i = 0; i < 8; ++i) q = fmaf(dx[i], dx[i], q);
  q = wave_sum(q);
  float rinv = 1.f / sqrtf(q * (1.f / 512.f) + 1e-5f);
  float4 g0 = LD4(g + lane * 4), g1 = LD4(g + 256 + lane * 4);
  float4 b0 = LD4(bt + lane * 4), b1 = LD4(bt + 256 + lane * 4);
  float o0[4] = {dx[0] * rinv * g0.x + b0.x, dx[1] * rinv * g0.y + b0.y,
                 dx[2] * rinv * g0.z + b0.z, dx[3] * rinv * g0.w + b0.w};
  float o1[4] = {dx[4] * rinv * g1.x + b1.x, dx[5] * rinv * g1.y + b1.y,
                 dx[6] * rinv * g1.z + b1.z, dx[7] * rinv * g1.w + b1.w};
  if (BF16OUT) {
    unsigned short* o16 = (unsigned short*)outp;
    uint2 u0, u1;
    u0.x = (unsigned)f2bf(o0[0]) | ((unsigned)f2bf(o0[1]) << 16);
    u0.y = (unsigned)f2bf(o0[2]) | ((unsigned)f2bf(o0[3]) << 16);
    u1.x = (unsigned)f2bf(o1[0]) | ((unsigned)f2bf(o1[1]) << 16);
    u1.y = (unsigned)f2bf(o1[2]) | ((unsigned)f2bf(o1[3]) << 16);
    *(uint2*)(o16 + (size_t)row * outstride + lane * 4) = u0;
    *(uint2*)(o16 + (size_t)row * outstride + 256 + lane * 4) = u1;
  } else {
    float* of = (float*)outp;
    *(float4*)(of + (size_t)row * outstride + lane * 4) = make_float4(o0[0], o0[1], o0[2], o0[3]);
    *(float4*)(of + (size_t)row * outstride + 256 + lane * 4) = make_float4(o1[0], o1[1], o1[2], o1[3]);
  }
}

// ---------------- weight transpose+convert: W[K][N] f32 -> Wt[N][K] bf16 -----
// blockIdx.z: 0 in_proj(512,1536,@0) 1 out_proj(512,512,@786432)
//             2 ff1(512,1024,@1048576) 3 ff2(1024,512,@1572864)
__global__ __launch_bounds__(256) void wconv_k(const float* __restrict__ iw,
                                               const float* __restrict__ ow,
                                               const float* __restrict__ f1,
                                               const float* __restrict__ f2,
                                               unsigned short* __restrict__ wt, int layer) {
  int mid = blockIdx.z;
  int K, N; const float* src; size_t ooff;
  if (mid == 0)      { K = 512;  N = 1536; src = iw + (size_t)layer * 512 * 1536; ooff = 0; }
  else if (mid == 1) { K = 512;  N = 512;  src = ow + (size_t)layer * 512 * 512;  ooff = 786432; }
  else if (mid == 2) { K = 512;  N = 1024; src = f1 + (size_t)layer * 512 * 1024; ooff = 1048576; }
  else               { K = 1024; N = 512;  src = f2 + (size_t)layer * 1024 * 512; ooff = 1572864; }
  int k0 = blockIdx.x * 64, n0 = blockIdx.y * 64;
  if (k0 >= K || n0 >= N) return;
  __shared__ float T[64][68];
  int t = threadIdx.x;
  {
    int r = t >> 2, c4 = (t & 3) * 16;
    const float* sp = src + (size_t)(k0 + r) * N + n0 + c4;
    *(float4*)&T[r][c4 + 0] = LD4(sp + 0);
    *(float4*)&T[r][c4 + 4] = LD4(sp + 4);
    *(float4*)&T[r][c4 + 8] = LD4(sp + 8);
    *(float4*)&T[r][c4 + 12] = LD4(sp + 12);
  }
  __syncthreads();
  {
    int n = t >> 2, k4 = (t & 3) * 16;
    union { unsigned short s[16]; uint4 v[2]; } u;
#pragma unroll
    for (int j = 0; j < 16; ++j) u.s[j] = f2bf(T[k4 + j][n]);
    uint4* dst = (uint4*)(wt + ooff + (size_t)(n0 + n) * K + k0 + k4);
    dst[0] = u.v[0];
    dst[1] = u.v[1];
  }
}

// ---------------- bf16 MFMA GEMM: out = A[M,K] @ Wt[N,K]^T (+bias)(+gelu/res)
// 128x128 tile, BK=32, 256 threads (2x2 waves of 64x64).
// LDS layout: [row][chunk swizzle] - elem(row,k) = row*32 + (k&7) + (((k>>3)^(row&3))<<3)
// Fragments: mfma_f32_16x16x32_bf16; A-lane: row=l&15, k=(l>>4)*8+j (contig 8)
//            B-lane: col=l&15, k=(l>>4)*8+j ; C/D: col=l&15, row=(l>>4)*4+reg
// EPI: 0 = +bias -> f32 ; 1 = gelu(+bias) -> bf16 ; 2 = +bias+res -> f32
template <int EPI, bool A_F32>
__global__ __launch_bounds__(256) void gemm_bf_k(const void* __restrict__ Ap,
                                                 const unsigned short* __restrict__ Wt,
                                                 const float* __restrict__ bias,
                                                 const float* __restrict__ res,
                                                 void* __restrict__ outp, int M, int N, int K) {
  __shared__ short As[128 * 32];
  __shared__ short Bs[128 * 32];
  const int tid = threadIdx.x;
  const int l = tid & 63, w = tid >> 6;
  const int bm = blockIdx.y * 128, bn = blockIdx.x * 128;
  const int srow = tid >> 1, sseg = tid & 1;  // staging: row 0..127, 16-elem segment 0..1
  f32x4 zero4 = {0.f, 0.f, 0.f, 0.f};
  f32x4 acc[4][4];
#pragma unroll
  for (int m = 0; m < 4; ++m)
#pragma unroll
    for (int n = 0; n < 4; ++n) acc[m][n] = zero4;

  const int c0 = sseg * 2, c1 = sseg * 2 + 1;
  const int aw0 = srow * 32 + ((c0 ^ (srow & 3)) << 3);
  const int aw1 = srow * 32 + ((c1 ^ (srow & 3)) << 3);

  for (int kt = 0; kt < K; kt += 32) {
    bf16x8 d0, d1;
    int gr = bm + srow;
    if (!A_F32) {
      if (gr < M) {
        const unsigned short* ap = (const unsigned short*)Ap + (size_t)gr * K + kt + sseg * 16;
        d0 = *(const bf16x8*)ap;
        d1 = *(const bf16x8*)(ap + 8);
      } else {
        d0 = (bf16x8){0, 0, 0, 0, 0, 0, 0, 0};
        d1 = d0;
      }
    } else {
      union { short s[16]; bf16x8 v[2]; } u;
      if (gr < M) {
        const float* ap = (const float*)Ap + (size_t)gr * K + kt + sseg * 16;
        float4 f0 = LD4(ap), f1 = LD4(ap + 4), f2 = LD4(ap + 8), f3 = LD4(ap + 12);
        float fv[16] = {f0.x, f0.y, f0.z, f0.w, f1.x, f1.y, f1.z, f1.w,
                        f2.x, f2.y, f2.z, f2.w, f3.x, f3.y, f3.z, f3.w};
#pragma unroll
        for (int j = 0; j < 16; ++j) u.s[j] = (short)f2bf(fv[j]);
      } else {
#pragma unroll
        for (int j = 0; j < 16; ++j) u.s[j] = 0;
      }
      d0 = u.v[0];
      d1 = u.v[1];
    }
    *(bf16x8*)&As[aw0] = d0;
    *(bf16x8*)&As[aw1] = d1;
    // B: Wt[bn+srow][kt + sseg*16 ..]
    const unsigned short* bp = Wt + (size_t)(bn + srow) * K + kt + sseg * 16;
    bf16x8 e0 = *(const bf16x8*)bp;
    bf16x8 e1 = *(const bf16x8*)(bp + 8);
    *(bf16x8*)&Bs[aw0] = e0;
    *(bf16x8*)&Bs[aw1] = e1;
    __syncthreads();

    bf16x8 af[4], bfr[4];
    const int ch = l >> 4;
#pragma unroll
    for (int m = 0; m < 4; ++m) {
      int r = (w >> 1) * 64 + m * 16 + (l & 15);
      af[m] = *(const bf16x8*)&As[r * 32 + ((ch ^ (r & 3)) << 3)];
    }
#pragma unroll
    for (int n = 0; n < 4; ++n) {
      int c = (w & 1) * 64 + n * 16 + (l & 15);
      bfr[n] = *(const bf16x8*)&Bs[c * 32 + ((ch ^ (c & 3)) << 3)];
    }
#pragma unroll
    for (int m = 0; m < 4; ++m)
#pragma unroll
      for (int n = 0; n < 4; ++n)
        acc[m][n] = __builtin_amdgcn_mfma_f32_16x16x32_bf16(af[m], bfr[n], acc[m][n], 0, 0, 0);
    __syncthreads();
  }

  const int rbase = bm + (w >> 1) * 64 + (l >> 4) * 4;
  const int cbase = bn + (w & 1) * 64 + (l & 15);
#pragma unroll
  for (int n = 0; n < 4; ++n) {
    int gc = cbase + n * 16;
    float bv = bias[gc];
#pragma unroll
    for (int m = 0; m < 4; ++m) {
#pragma unroll
      for (int rg = 0; rg < 4; ++rg) {
        int gr = rbase + m * 16 + rg;
        if (gr >= M) continue;
        float v = acc[m][n][rg] + bv;
        if (EPI == 1) {
          v = gelu_f(v);
          ((unsigned short*)outp)[(size_t)gr * N + gc] = f2bf(v);
        } else {
          if (EPI == 2) v += res[(size_t)gr * N + gc];
          ((float*)outp)[(size_t)gr * N + gc] = v;
        }
      }
    }
  }
}

// ---------------- fused flash attention (unchanged this round) ---------------
__global__ __launch_bounds__(256) void attn_k(const float* __restrict__ qkv,
                                              const float* __restrict__ bias,
                                              float* __restrict__ o) {
  __shared__ float Kt[64][65];
  __shared__ float Vt[64][64];
  __shared__ float Qt[64][64];
  float* Pt = &Kt[0][0];  // alias: w*1024 + j*16 + r (4096 <= 4160)
  const int tid = threadIdx.x;
  const int lane = tid & 63;
  const int w = tid >> 6;
  const int h = blockIdx.y, b = blockIdx.z;
  const int i0 = blockIdx.x * 64;
  const float* qk = qkv + (size_t)b * NSEQ * 1536;
#pragma unroll
  for (int rr = 0; rr < 16; ++rr) {
    int r = w + rr * 4;
    int ig = i0 + r;
    Qt[lane][r] = (ig < NSEQ) ? qk[(size_t)ig * 1536 + h * 64 + lane] : 0.f;
  }
  float m_r[16], l_r[16], o_acc[16];
#pragma unroll
  for (int r = 0; r < 16; ++r) { m_r[r] = -1e30f; l_r[r] = 0.f; o_acc[r] = 0.f; }
  for (int j0 = 0; j0 < NSEQ; j0 += 64) {
    __syncthreads();
#pragma unroll
    for (int rr = 0; rr < 16; ++rr) {
      int r = w + rr * 4;
      int jg = j0 + r;
      float kv = 0.f, vv = 0.f;
      if (jg < NSEQ) {
        kv = qk[(size_t)jg * 1536 + 512 + h * 64 + lane];
        vv = qk[(size_t)jg * 1536 + 1024 + h * 64 + lane];
      }
      Kt[r][lane] = kv;
      Vt[r][lane] = vv;
    }
    __syncthreads();
    float s[16];
#pragma unroll
    for (int r = 0; r < 16; ++r) s[r] = 0.f;
#pragma unroll 4
    for (int d = 0; d < 64; ++d) {
      float kvd = Kt[lane][d];
#pragma unroll
      for (int q4 = 0; q4 < 4; ++q4) {
        float4 qv = LD4(&Qt[d][w * 16 + q4 * 4]);
        s[q4 * 4 + 0] = fmaf(qv.x, kvd, s[q4 * 4 + 0]);
        s[q4 * 4 + 1] = fmaf(qv.y, kvd, s[q4 * 4 + 1]);
        s[q4 * 4 + 2] = fmaf(qv.z, kvd, s[q4 * 4 + 2]);
        s[q4 * 4 + 3] = fmaf(qv.w, kvd, s[q4 * 4 + 3]);
      }
    }
    __syncthreads();
    int jg = j0 + lane;
    bool jv = jg < NSEQ;
#pragma unroll
    for (int q4 = 0; q4 < 4; ++q4) {
      float pv[4];
#pragma unroll
      for (int k = 0; k < 4; ++k) {
        int r = q4 * 4 + k;
        int ig = i0 + w * 16 + r;
        float sv = s[r] * 0.125f;
        if (jv && ig < NSEQ) sv += bias[((size_t)b * NSEQ + ig) * NSEQ + jg];
        if (!jv) sv = -1e30f;
        float mt = wave_max(sv);
        float mnew = fmaxf(m_r[r], mt);
        float fct = __expf(m_r[r] - mnew);
        float p = __expf(sv - mnew);
        float ls = wave_sum(p);
        l_r[r] = l_r[r] * fct + ls;
        m_r[r] = mnew;
        o_acc[r] *= fct;
        pv[k] = p;
      }
      *(float4*)(&Pt[w * 1024 + lane * 16 + q4 * 4]) = make_float4(pv[0], pv[1], pv[2], pv[3]);
    }
#pragma unroll 4
    for (int j = 0; j < 64; ++j) {
      float vv = Vt[j][lane];
#pragma unroll
      for (int q4 = 0; q4 < 4; ++q4) {
        float4 p4 = LD4(&Pt[w * 1024 + j * 16 + q4 * 4]);
        o_acc[q4 * 4 + 0] = fmaf(p4.x, vv, o_acc[q4 * 4 + 0]);
        o_acc[q4 * 4 + 1] = fmaf(p4.y, vv, o_acc[q4 * 4 + 1]);
        o_acc[q4 * 4 + 2] = fmaf(p4.z, vv, o_acc[q4 * 4 + 2]);
        o_acc[q4 * 4 + 3] = fmaf(p4.w, vv, o_acc[q4 * 4 + 3]);
      }
    }
  }
#pragma unroll
  for (int r = 0; r < 16; ++r) {
    int ig = i0 + w * 16 + r;
    if (ig < NSEQ) o[((size_t)b * NSEQ + ig) * DM + h * 64 + lane] = o_acc[r] / l_r[r];
  }
}

// ---------------- head -------------------------------------------------------
__global__ __launch_bounds__(256) void head_k(const float* __restrict__ x0,
                                              const float* __restrict__ head_w,
                                              const float* __restrict__ head_b,
                                              float* __restrict__ outp) {
  __shared__ float xs[512];
  int b = blockIdx.y;
  for (int c = threadIdx.x; c < 512; c += 256) xs[c] = x0[b * 512 + c];
  __syncthreads();
  int j = blockIdx.x * 256 + threadIdx.x;
  if (j >= 4273) return;
  float acc = head_b[j];
  for (int k = 0; k < 512; ++k) acc = fmaf(xs[k], head_w[(size_t)k * 4273 + j], acc);
  outp[(size_t)b * 4273 + j] = acc;
}

extern "C" void kernel_launch(void* const* d_in, const int* in_sizes, int n_in,
                              void* d_out, int out_size, void* d_ws, size_t ws_size,
                              hipStream_t stream) {
  const float* seq_embed = (const float*)d_in[0];
  const float* pae = (const float*)d_in[1];
  const float* plddt = (const float*)d_in[2];
  const float* centroid = (const float*)d_in[3];
  const float* orientv = (const float*)d_in[4];
  const float* scv = (const float*)d_in[5];
  const float* eucl = (const float*)d_in[6];
  const float* edgev = (const float*)d_in[7];
  const float* input_proj_w = (const float*)d_in[8];
  const float* input_proj_b = (const float*)d_in[9];
  const float* plddt_w = (const float*)d_in[10];
  const float* plddt_b = (const float*)d_in[11];
  const float* cent_w = (const float*)d_in[12];
  const float* cent_b = (const float*)d_in[13];
  const float* orient_w = (const float*)d_in[14];
  const float* orient_b = (const float*)d_in[15];
  const float* sc_w = (const float*)d_in[16];
  const float* sc_b = (const float*)d_in[17];
  const float* fusion_w = (const float*)d_in[18];
  const float* fusion_b = (const float*)d_in[19];
  const float* pair_w = (const float*)d_in[20];
  const float* pair_b = (const float*)d_in[21];
  const float* pos_enc = (const float*)d_in[22];
  const float* cls_token = (const float*)d_in[23];
  const float* rel_emb = (const float*)d_in[24];
  const float* ln1_g = (const float*)d_in[25];
  const float* ln1_b = (const float*)d_in[26];
  const float* ln2_g = (const float*)d_in[27];
  const float* ln2_b = (const float*)d_in[28];
  const float* in_proj_w = (const float*)d_in[29];
  const float* in_proj_b = (const float*)d_in[30];
  const float* out_proj_w = (const float*)d_in[31];
  const float* out_proj_b = (const float*)d_in[32];
  const float* ff1_w = (const float*)d_in[33];
  const float* ff1_b = (const float*)d_in[34];
  const float* ff2_w = (const float*)d_in[35];
  const float* ff2_b = (const float*)d_in[36];
  const float* norm_g = (const float*)d_in[37];
  const float* norm_b = (const float*)d_in[38];
  const float* head_w = (const float*)d_in[39];
  const float* head_b = (const float*)d_in[40];
  float* outp = (float*)d_out;

  char* ws = (char*)d_ws;
  size_t off = 0;
  auto alloc = [&](size_t bytes) -> void* {
    void* p = (void*)(ws + off);
    off = (off + bytes + 255) & ~(size_t)255;
    return p;
  };
  float* Wc = (float*)alloc((size_t)2560 * 512 * 4);
  float* vecb = (float*)alloc(5632 * 4);
  float* rel = (float*)alloc(2049 * 4);
  float* x = (float*)alloc((size_t)BATCH * NSEQ * DM * 4);
  float* biasb = (float*)alloc((size_t)BATCH * NSEQ * NSEQ * 4);
  unsigned short* z16 = (unsigned short*)alloc((size_t)4100 * 512 * 2);
  float* qkvb = (float*)alloc((size_t)BATCH * NSEQ * 1536 * 4);
  float* attb = (float*)alloc((size_t)BATCH * NSEQ * DM * 4);
  unsigned short* hbuf16 = (unsigned short*)alloc((size_t)4100 * 1024 * 2);
  unsigned short* wt = (unsigned short*)alloc((size_t)2097152 * 2);
  float* x0 = (float*)alloc(4 * 512 * 4);
  (void)ws_size; (void)in_sizes; (void)n_in; (void)out_size;

  relbias_k<<<9, 256, 0, stream>>>(rel_emb, rel);
  prepvec_k<<<2, 256, 0, stream>>>(plddt_w, plddt_b, cent_w, cent_b, orient_w, orient_b,
                                   sc_w, sc_b, input_proj_b, fusion_w, fusion_b, cls_token,
                                   vecb, x);
  gemm_k<0><<<dim3(8, 40), 256, 0, stream>>>(input_proj_w, fusion_w, nullptr, nullptr, Wc,
                                             2560, 512, 512);
  gemm_embed_k<<<dim3(8, 64), 256, 0, stream>>>(seq_embed, Wc, vecb, plddt, centroid, orientv,
                                                scv, pos_enc, x);
  pairbias_k<<<BATCH * NSEQ, 256, 0, stream>>>(eucl, pae, edgev, pair_w, pair_b, rel, biasb);

  for (int l = 0; l < 6; ++l) {
    wconv_k<<<dim3(16, 24, 4), 256, 0, stream>>>(in_proj_w, out_proj_w, ff1_w, ff2_w, wt, l);
    ln_k<true><<<4100, 64, 0, stream>>>(x, z16, ln1_g + l * 512, ln1_b + l * 512, 4100, 512, 512);
    gemm_bf_k<0, false><<<dim3(12, 33), 256, 0, stream>>>(z16, wt, in_proj_b + (size_t)l * 1536,
                                                          nullptr, qkvb, 4100, 1536, 512);
    attn_k<<<dim3(17, 8, 4), 256, 0, stream>>>(qkvb, biasb, attb);
    gemm_bf_k<2, true><<<dim3(4, 33), 256, 0, stream>>>(attb, wt + 786432,
                                                        out_proj_b + (size_t)l * 512, x, x,
                                                        4100, 512, 512);
    ln_k<true><<<4100, 64, 0, stream>>>(x, z16, ln2_g + l * 512, ln2_b + l * 512, 4100, 512, 512);
    gemm_bf_k<1, false><<<dim3(8, 33), 256, 0, stream>>>(z16, wt + 1048576,
                                                         ff1_b + (size_t)l * 1024, nullptr,
                                                         hbuf16, 4100, 1024, 512);
    gemm_bf_k<2, false><<<dim3(4, 33), 256, 0, stream>>>(hbuf16, wt + 1572864,
                                                         ff2_b + (size_t)l * 512, x, x,
                                                         4100, 512, 1024);
  }
  ln_k<false><<<4, 64, 0, stream>>>(x, x0, norm_g, norm_b, 4, NSEQ * DM, 512);
  head_k<<<dim3(17, 4), 256, 0, stream>>>(x0, head_w, head_b, outp);
}

// Round 7
// 2249.325 us; speedup vs baseline: 2.9359x; 2.5032x over previous
//
#include <hip/hip_runtime.h>
#include <math.h>

#define DM 512
#define NSEQ 1025
#define BATCH 4

#define LD4(p) (*(const float4*)(p))

typedef __attribute__((ext_vector_type(8))) short bf16x8;
typedef __attribute__((ext_vector_type(4))) float f32x4;

__device__ __forceinline__ float wave_sum(float v) {
#pragma unroll
  for (int off = 32; off > 0; off >>= 1) v += __shfl_xor(v, off, 64);
  return v;
}
__device__ __forceinline__ float4 f4fma(float s, float4 a, float4 acc) {
  acc.x = fmaf(s, a.x, acc.x); acc.y = fmaf(s, a.y, acc.y);
  acc.z = fmaf(s, a.z, acc.z); acc.w = fmaf(s, a.w, acc.w);
  return acc;
}
__device__ __forceinline__ float4 f4add(float4 a, float4 b) {
  a.x += b.x; a.y += b.y; a.z += b.z; a.w += b.w; return a;
}
__device__ __forceinline__ float gelu_f(float x) {
  return 0.5f * x * (1.0f + erff(x * 0.70710678118654752f));
}
__device__ __forceinline__ unsigned short f2bf(float f) {
  unsigned u = __float_as_uint(f);
  u += 0x7FFFu + ((u >> 16) & 1u);
  return (unsigned short)(u >> 16);
}

// ---------------- rel-position bias table ------------------------------------
__global__ void relbias_k(const float* __restrict__ rel_emb, float* __restrict__ rel) {
  int r = blockIdx.x * 256 + threadIdx.x;
  if (r >= 2049) return;
  int relpos = r - 1024;
  int so = (relpos < 0) ? 16 : 0;
  int dist = (relpos < 0) ? -relpos : relpos;
  int bucket;
  if (dist < 16) {
    bucket = dist;
  } else {
    float large = fminf((float)dist, 128.f);
    float lr = (float)2.0794415416798357;
    float lb = logf(large * (1.f / 16.f) + 1e-8f) / lr * 15.f;
    bucket = (int)lb + 16;
  }
  bucket += so;
  bucket = bucket < 0 ? 0 : (bucket > 31 ? 31 : bucket);
  rel[r] = rel_emb[bucket];
}

// ---------------- small weight prep ------------------------------------------
__global__ void prepvec_k(const float* __restrict__ plddt_w, const float* __restrict__ plddt_b,
                          const float* __restrict__ cent_w, const float* __restrict__ cent_b,
                          const float* __restrict__ orient_w, const float* __restrict__ orient_b,
                          const float* __restrict__ sc_w, const float* __restrict__ sc_b,
                          const float* __restrict__ input_proj_b,
                          const float* __restrict__ fusion_w, const float* __restrict__ fusion_b,
                          const float* __restrict__ cls, float* __restrict__ vecb,
                          float* __restrict__ x) {
  int n = blockIdx.x * 256 + threadIdx.x;
  if (n >= 512) return;
  float vp = 0.f, cv = 0.f;
  float mc[3] = {0.f, 0.f, 0.f}, mo[3] = {0.f, 0.f, 0.f}, ms[3] = {0.f, 0.f, 0.f};
  for (int m = 0; m < 512; ++m) {
    float f0 = fusion_w[(size_t)m * 512 + n];
    float f1 = fusion_w[(size_t)(512 + m) * 512 + n];
    float f2 = fusion_w[(size_t)(1024 + m) * 512 + n];
    float f3 = fusion_w[(size_t)(1536 + m) * 512 + n];
    float f4 = fusion_w[(size_t)(2048 + m) * 512 + n];
    vp = fmaf(plddt_w[m], f1, vp);
    cv = fmaf(input_proj_b[m], f0, cv);
    cv = fmaf(plddt_b[m], f1, cv);
    cv = fmaf(cent_b[m], f2, cv);
    cv = fmaf(orient_b[m], f3, cv);
    cv = fmaf(sc_b[m], f4, cv);
#pragma unroll
    for (int c = 0; c < 3; ++c) {
      mc[c] = fmaf(cent_w[c * 512 + m], f2, mc[c]);
      mo[c] = fmaf(orient_w[c * 512 + m], f3, mo[c]);
      ms[c] = fmaf(sc_w[c * 512 + m], f4, ms[c]);
    }
  }
  cv += fusion_b[n];
  vecb[n] = vp;
#pragma unroll
  for (int c = 0; c < 3; ++c) {
    vecb[512 + c * 512 + n] = mc[c];
    vecb[2048 + c * 512 + n] = mo[c];
    vecb[3584 + c * 512 + n] = ms[c];
  }
  vecb[5120 + n] = cv;
  float cl = cls[n];
  for (int b = 0; b < 4; ++b) x[((size_t)b * NSEQ) * DM + n] = cl;
}

// ---------------- generic fp32 GEMM (Wc / embed) -----------------------------
template <int EPI>
__global__ __launch_bounds__(256) void gemm_k(const float* __restrict__ A,
                                              const float* __restrict__ W,
                                              const float* __restrict__ bias,
                                              const float* __restrict__ res,
                                              float* __restrict__ out, int M, int N, int K) {
  __shared__ float As[16][72];
  __shared__ float Bs[16][72];
  const int tid = threadIdx.x;
  const int tx = tid & 15, ty = tid >> 4;
  const int bm = blockIdx.y * 64, bn = blockIdx.x * 64;
  const int arow = bm + (tid >> 2);
  const int akq = (tid & 3) * 4;
  const int brow = tid >> 4;
  const int bcol = bn + tx * 4;
  float acc[4][4] = {};
  for (int kt = 0; kt < K; kt += 16) {
    float4 av = make_float4(0.f, 0.f, 0.f, 0.f);
    if (arow < M) av = LD4(A + (size_t)arow * K + kt + akq);
    float4 bv = LD4(W + (size_t)(kt + brow) * N + bcol);
    As[akq + 0][tid >> 2] = av.x;
    As[akq + 1][tid >> 2] = av.y;
    As[akq + 2][tid >> 2] = av.z;
    As[akq + 3][tid >> 2] = av.w;
    *(float4*)(&Bs[brow][tx * 4]) = bv;
    __syncthreads();
#pragma unroll
    for (int kk = 0; kk < 16; ++kk) {
      float4 a4 = LD4(&As[kk][ty * 4]);
      float4 b4 = LD4(&Bs[kk][tx * 4]);
      float aa[4] = {a4.x, a4.y, a4.z, a4.w};
      float bb[4] = {b4.x, b4.y, b4.z, b4.w};
#pragma unroll
      for (int i = 0; i < 4; ++i)
#pragma unroll
        for (int j = 0; j < 4; ++j) acc[i][j] = fmaf(aa[i], bb[j], acc[i][j]);
    }
    __syncthreads();
  }
  const int gn = bn + tx * 4;
  float4 bb4 = make_float4(0.f, 0.f, 0.f, 0.f);
  if (bias) bb4 = LD4(bias + gn);
#pragma unroll
  for (int ii = 0; ii < 4; ++ii) {
    int gm = bm + ty * 4 + ii;
    if (gm >= M) continue;
    float4 v = make_float4(acc[ii][0], acc[ii][1], acc[ii][2], acc[ii][3]);
    v = f4add(v, bb4);
    if (EPI == 1) {
      v.x = gelu_f(v.x); v.y = gelu_f(v.y); v.z = gelu_f(v.z); v.w = gelu_f(v.w);
    }
    if (EPI == 2) v = f4add(v, LD4(res + (size_t)gm * N + gn));
    *(float4*)(out + (size_t)gm * N + gn) = v;
  }
}

// ---------------- embedding GEMM ---------------------------------------------
__global__ __launch_bounds__(256) void gemm_embed_k(const float* __restrict__ A,
                                                    const float* __restrict__ W,
                                                    const float* __restrict__ vecb,
                                                    const float* __restrict__ plddt,
                                                    const float* __restrict__ cent,
                                                    const float* __restrict__ orient,
                                                    const float* __restrict__ scv,
                                                    const float* __restrict__ pos_enc,
                                                    float* __restrict__ x) {
  const int K = 2560, N = 512;
  __shared__ float As[16][72];
  __shared__ float Bs[16][72];
  const int tid = threadIdx.x;
  const int tx = tid & 15, ty = tid >> 4;
  const int bm = blockIdx.y * 64, bn = blockIdx.x * 64;
  const int arow = bm + (tid >> 2);
  const int akq = (tid & 3) * 4;
  const int brow = tid >> 4;
  const int bcol = bn + tx * 4;
  float acc[4][4] = {};
  for (int kt = 0; kt < K; kt += 16) {
    float4 av = LD4(A + (size_t)arow * K + kt + akq);
    float4 bv = LD4(W + (size_t)(kt + brow) * N + bcol);
    As[akq + 0][tid >> 2] = av.x;
    As[akq + 1][tid >> 2] = av.y;
    As[akq + 2][tid >> 2] = av.z;
    As[akq + 3][tid >> 2] = av.w;
    *(float4*)(&Bs[brow][tx * 4]) = bv;
    __syncthreads();
#pragma unroll
    for (int kk = 0; kk < 16; ++kk) {
      float4 a4 = LD4(&As[kk][ty * 4]);
      float4 b4 = LD4(&Bs[kk][tx * 4]);
      float aa[4] = {a4.x, a4.y, a4.z, a4.w};
      float bb[4] = {b4.x, b4.y, b4.z, b4.w};
#pragma unroll
      for (int i = 0; i < 4; ++i)
#pragma unroll
        for (int j = 0; j < 4; ++j) acc[i][j] = fmaf(aa[i], bb[j], acc[i][j]);
    }
    __syncthreads();
  }
  const int gn = bn + tx * 4;
  float4 vp4 = LD4(vecb + gn);
  float4 mc0 = LD4(vecb + 512 + gn), mc1 = LD4(vecb + 1024 + gn), mc2 = LD4(vecb + 1536 + gn);
  float4 mo0 = LD4(vecb + 2048 + gn), mo1 = LD4(vecb + 2560 + gn), mo2 = LD4(vecb + 3072 + gn);
  float4 ms0 = LD4(vecb + 3584 + gn), ms1 = LD4(vecb + 4096 + gn), ms2 = LD4(vecb + 4608 + gn);
  float4 cv4 = LD4(vecb + 5120 + gn);
#pragma unroll
  for (int ii = 0; ii < 4; ++ii) {
    int gm = bm + ty * 4 + ii;
    int b = gm >> 10, i = gm & 1023;
    float4 v = make_float4(acc[ii][0], acc[ii][1], acc[ii][2], acc[ii][3]);
    v = f4add(v, cv4);
    v = f4fma(plddt[gm], vp4, v);
    const float* cp = cent + 3 * (size_t)gm;
    v = f4fma(cp[0], mc0, v); v = f4fma(cp[1], mc1, v); v = f4fma(cp[2], mc2, v);
    const float* op2 = orient + 3 * (size_t)gm;
    v = f4fma(op2[0], mo0, v); v = f4fma(op2[1], mo1, v); v = f4fma(op2[2], mo2, v);
    const float* sp = scv + 3 * (size_t)gm;
    v = f4fma(sp[0], ms0, v); v = f4fma(sp[1], ms1, v); v = f4fma(sp[2], ms2, v);
    v = f4add(v, LD4(pos_enc + (size_t)i * 512 + gn));
    *(float4*)(x + ((size_t)(b * NSEQ + 1 + i)) * DM + gn) = v;
  }
}

// ---------------- pair bias --------------------------------------------------
__global__ __launch_bounds__(256) void pairbias_k(const float* __restrict__ ed,
                                                  const float* __restrict__ pae,
                                                  const float* __restrict__ ev,
                                                  const float* __restrict__ pair_w,
                                                  const float* __restrict__ pair_b,
                                                  const float* __restrict__ rel,
                                                  float* __restrict__ biasb) {
  int rowid = blockIdx.x;
  int b = rowid / NSEQ, ii = rowid % NSEQ;
  float w0 = pair_w[0], w1 = pair_w[1], w2 = pair_w[2], w3 = pair_w[3], w4 = pair_w[4];
  float pb = pair_b[0];
  float* orow = biasb + ((size_t)b * NSEQ + ii) * NSEQ;
  for (int jj = threadIdx.x; jj < NSEQ; jj += 256) {
    float v = rel[jj - ii + 1024];
    if (ii > 0 && jj > 0) {
      size_t e = ((size_t)b * 1024 + (ii - 1)) * 1024 + (jj - 1);
      v += ed[e] * w0 + pae[e] * w1 + ev[3 * e] * w2 + ev[3 * e + 1] * w3 + ev[3 * e + 2] * w4 + pb;
    }
    orow[jj] = v;
  }
}

// ---------------- LayerNorm (optional bf16 out) ------------------------------
template <bool BF16OUT>
__global__ __launch_bounds__(64) void ln_k(const float* __restrict__ in, void* __restrict__ outp,
                                           const float* __restrict__ g, const float* __restrict__ bt,
                                           int nrows, int instride, int outstride) {
  int row = blockIdx.x;
  if (row >= nrows) return;
  int lane = threadIdx.x;
  const float* p = in + (size_t)row * instride;
  float4 a = LD4(p + lane * 4);
  float4 c = LD4(p + 256 + lane * 4);
  float s = a.x + a.y + a.z + a.w + c.x + c.y + c.z + c.w;
  s = wave_sum(s);
  float m = s * (1.f / 512.f);
  float dx[8] = {a.x - m, a.y - m, a.z - m, a.w - m, c.x - m, c.y - m, c.z - m, c.w - m};
  float q = 0.f;
#pragma unroll
  for (int i = 0; i < 8; ++i) q = fmaf(dx[i], dx[i], q);
  q = wave_sum(q);
  float rinv = 1.f / sqrtf(q * (1.f / 512.f) + 1e-5f);
  float4 g0 = LD4(g + lane * 4), g1 = LD4(g + 256 + lane * 4);
  float4 b0 = LD4(bt + lane * 4), b1 = LD4(bt + 256 + lane * 4);
  float o0[4] = {dx[0] * rinv * g0.x + b0.x, dx[1] * rinv * g0.y + b0.y,
                 dx[2] * rinv * g0.z + b0.z, dx[3] * rinv * g0.w + b0.w};
  float o1[4] = {dx[4] * rinv * g1.x + b1.x, dx[5] * rinv * g1.y + b1.y,
                 dx[6] * rinv * g1.z + b1.z, dx[7] * rinv * g1.w + b1.w};
  if (BF16OUT) {
    unsigned short* o16 = (unsigned short*)outp;
    uint2 u0, u1;
    u0.x = (unsigned)f2bf(o0[0]) | ((unsigned)f2bf(o0[1]) << 16);
    u0.y = (unsigned)f2bf(o0[2]) | ((unsigned)f2bf(o0[3]) << 16);
    u1.x = (unsigned)f2bf(o1[0]) | ((unsigned)f2bf(o1[1]) << 16);
    u1.y = (unsigned)f2bf(o1[2]) | ((unsigned)f2bf(o1[3]) << 16);
    *(uint2*)(o16 + (size_t)row * outstride + lane * 4) = u0;
    *(uint2*)(o16 + (size_t)row * outstride + 256 + lane * 4) = u1;
  } else {
    float* of = (float*)outp;
    *(float4*)(of + (size_t)row * outstride + lane * 4) = make_float4(o0[0], o0[1], o0[2], o0[3]);
    *(float4*)(of + (size_t)row * outstride + 256 + lane * 4) = make_float4(o1[0], o1[1], o1[2], o1[3]);
  }
}

// ---------------- weight transpose+convert -----------------------------------
__global__ __launch_bounds__(256) void wconv_k(const float* __restrict__ iw,
                                               const float* __restrict__ ow,
                                               const float* __restrict__ f1,
                                               const float* __restrict__ f2,
                                               unsigned short* __restrict__ wt, int layer) {
  int mid = blockIdx.z;
  int K, N; const float* src; size_t ooff;
  if (mid == 0)      { K = 512;  N = 1536; src = iw + (size_t)layer * 512 * 1536; ooff = 0; }
  else if (mid == 1) { K = 512;  N = 512;  src = ow + (size_t)layer * 512 * 512;  ooff = 786432; }
  else if (mid == 2) { K = 512;  N = 1024; src = f1 + (size_t)layer * 512 * 1024; ooff = 1048576; }
  else               { K = 1024; N = 512;  src = f2 + (size_t)layer * 1024 * 512; ooff = 1572864; }
  int k0 = blockIdx.x * 64, n0 = blockIdx.y * 64;
  if (k0 >= K || n0 >= N) return;
  __shared__ float T[64][68];
  int t = threadIdx.x;
  {
    int r = t >> 2, c4 = (t & 3) * 16;
    const float* sp = src + (size_t)(k0 + r) * N + n0 + c4;
    *(float4*)&T[r][c4 + 0] = LD4(sp + 0);
    *(float4*)&T[r][c4 + 4] = LD4(sp + 4);
    *(float4*)&T[r][c4 + 8] = LD4(sp + 8);
    *(float4*)&T[r][c4 + 12] = LD4(sp + 12);
  }
  __syncthreads();
  {
    int n = t >> 2, k4 = (t & 3) * 16;
    union { unsigned short s[16]; uint4 v[2]; } u;
#pragma unroll
    for (int j = 0; j < 16; ++j) u.s[j] = f2bf(T[k4 + j][n]);
    uint4* dst = (uint4*)(wt + ooff + (size_t)(n0 + n) * K + k0 + k4);
    dst[0] = u.v[0];
    dst[1] = u.v[1];
  }
}

// ---------------- bf16 MFMA GEMM ---------------------------------------------
// EPI: 0 = +bias -> f32 ; 1 = gelu(+bias) -> bf16 ; 2 = +bias+res -> f32 ; 3 = +bias -> bf16
template <int EPI, bool A_F32>
__global__ __launch_bounds__(256) void gemm_bf_k(const void* __restrict__ Ap,
                                                 const unsigned short* __restrict__ Wt,
                                                 const float* __restrict__ bias,
                                                 const float* __restrict__ res,
                                                 void* __restrict__ outp, int M, int N, int K) {
  __shared__ short As[128 * 32];
  __shared__ short Bs[128 * 32];
  const int tid = threadIdx.x;
  const int l = tid & 63, w = tid >> 6;
  const int bm = blockIdx.y * 128, bn = blockIdx.x * 128;
  const int srow = tid >> 1, sseg = tid & 1;
  f32x4 zero4 = {0.f, 0.f, 0.f, 0.f};
  f32x4 acc[4][4];
#pragma unroll
  for (int m = 0; m < 4; ++m)
#pragma unroll
    for (int n = 0; n < 4; ++n) acc[m][n] = zero4;

  const int c0 = sseg * 2, c1 = sseg * 2 + 1;
  const int aw0 = srow * 32 + ((c0 ^ (srow & 3)) << 3);
  const int aw1 = srow * 32 + ((c1 ^ (srow & 3)) << 3);

  for (int kt = 0; kt < K; kt += 32) {
    bf16x8 d0, d1;
    int gr = bm + srow;
    if (!A_F32) {
      if (gr < M) {
        const unsigned short* ap = (const unsigned short*)Ap + (size_t)gr * K + kt + sseg * 16;
        d0 = *(const bf16x8*)ap;
        d1 = *(const bf16x8*)(ap + 8);
      } else {
        d0 = (bf16x8){0, 0, 0, 0, 0, 0, 0, 0};
        d1 = d0;
      }
    } else {
      union { short s[16]; bf16x8 v[2]; } u;
      if (gr < M) {
        const float* ap = (const float*)Ap + (size_t)gr * K + kt + sseg * 16;
        float4 f0 = LD4(ap), f1 = LD4(ap + 4), f2 = LD4(ap + 8), f3 = LD4(ap + 12);
        float fv[16] = {f0.x, f0.y, f0.z, f0.w, f1.x, f1.y, f1.z, f1.w,
                        f2.x, f2.y, f2.z, f2.w, f3.x, f3.y, f3.z, f3.w};
#pragma unroll
        for (int j = 0; j < 16; ++j) u.s[j] = (short)f2bf(fv[j]);
      } else {
#pragma unroll
        for (int j = 0; j < 16; ++j) u.s[j] = 0;
      }
      d0 = u.v[0];
      d1 = u.v[1];
    }
    *(bf16x8*)&As[aw0] = d0;
    *(bf16x8*)&As[aw1] = d1;
    const unsigned short* bp = Wt + (size_t)(bn + srow) * K + kt + sseg * 16;
    bf16x8 e0 = *(const bf16x8*)bp;
    bf16x8 e1 = *(const bf16x8*)(bp + 8);
    *(bf16x8*)&Bs[aw0] = e0;
    *(bf16x8*)&Bs[aw1] = e1;
    __syncthreads();

    bf16x8 af[4], bfr[4];
    const int ch = l >> 4;
#pragma unroll
    for (int m = 0; m < 4; ++m) {
      int r = (w >> 1) * 64 + m * 16 + (l & 15);
      af[m] = *(const bf16x8*)&As[r * 32 + ((ch ^ (r & 3)) << 3)];
    }
#pragma unroll
    for (int n = 0; n < 4; ++n) {
      int c = (w & 1) * 64 + n * 16 + (l & 15);
      bfr[n] = *(const bf16x8*)&Bs[c * 32 + ((ch ^ (c & 3)) << 3)];
    }
#pragma unroll
    for (int m = 0; m < 4; ++m)
#pragma unroll
      for (int n = 0; n < 4; ++n)
        acc[m][n] = __builtin_amdgcn_mfma_f32_16x16x32_bf16(af[m], bfr[n], acc[m][n], 0, 0, 0);
    __syncthreads();
  }

  const int rbase = bm + (w >> 1) * 64 + (l >> 4) * 4;
  const int cbase = bn + (w & 1) * 64 + (l & 15);
#pragma unroll
  for (int n = 0; n < 4; ++n) {
    int gc = cbase + n * 16;
    float bv = bias[gc];
#pragma unroll
    for (int m = 0; m < 4; ++m) {
#pragma unroll
      for (int rg = 0; rg < 4; ++rg) {
        int gr = rbase + m * 16 + rg;
        if (gr >= M) continue;
        float v = acc[m][n][rg] + bv;
        if (EPI == 1 || EPI == 3) {
          if (EPI == 1) v = gelu_f(v);
          ((unsigned short*)outp)[(size_t)gr * N + gc] = f2bf(v);
        } else {
          if (EPI == 2) v += res[(size_t)gr * N + gc];
          ((float*)outp)[(size_t)gr * N + gc] = v;
        }
      }
    }
  }
}

// ---------------- MFMA flash attention ---------------------------------------
// grid (17, 8, 4), 256 thr = 4 waves x 16 q-rows. qkv bf16 row: [q k v] x 512.
// Per 64-col KV tile: Kl[64][72] bf16 row-major, Vt[64][72] bf16 = V^T ([d][j]).
// QK^T: A=Q-frag (regs), B=K rows.  C layout: row(q)=g*4+reg, col(j)=n*16+r.
// Softmax: reduce across 16-lane group (shfl_xor 1,2,4,8); online m/l.
// P -> bf16 -> Pl[w][16][72] -> A-frag reads; PV: B = Vt rows (d), k = j.
__global__ __launch_bounds__(256) void attn_k(const unsigned short* __restrict__ qkv,
                                              const float* __restrict__ bias,
                                              float* __restrict__ o) {
  __shared__ short Kl[64 * 72];
  __shared__ short Vt[64 * 72];
  __shared__ short Pl[4][16 * 72];
  const int tid = threadIdx.x;
  const int l = tid & 63, w = tid >> 6;
  const int g = l >> 4, r = l & 15;
  const int h = blockIdx.y, b = blockIdx.z;
  const int i0 = blockIdx.x * 64;
  const unsigned short* qb = qkv + (size_t)b * NSEQ * 1536;

  bf16x8 qf[2];
  {
    int qrow = i0 + w * 16 + r;
    if (qrow < NSEQ) {
      const unsigned short* qp = qb + (size_t)qrow * 1536 + h * 64 + g * 8;
      qf[0] = *(const bf16x8*)qp;
      qf[1] = *(const bf16x8*)(qp + 32);
    } else {
      qf[0] = (bf16x8){0, 0, 0, 0, 0, 0, 0, 0};
      qf[1] = qf[0];
    }
  }
  float m_r[4] = {-1e30f, -1e30f, -1e30f, -1e30f};
  float l_r[4] = {0.f, 0.f, 0.f, 0.f};
  f32x4 o4[4];
#pragma unroll
  for (int n = 0; n < 4; ++n) o4[n] = (f32x4){0.f, 0.f, 0.f, 0.f};

  const int kseg = tid & 3, krow = tid >> 2;  // K staging: row, 16-elem segment
  const int vd = tid & 63, vw4 = tid >> 6;    // V staging: d-lane, j-quad

  for (int j0 = 0; j0 < NSEQ; j0 += 64) {
    __syncthreads();
    {  // stage K rows (vector)
      int jg = j0 + krow;
      bf16x8 k0, k1;
      if (jg < NSEQ) {
        const unsigned short* kp = qb + (size_t)jg * 1536 + 512 + h * 64 + kseg * 16;
        k0 = *(const bf16x8*)kp;
        k1 = *(const bf16x8*)(kp + 8);
      } else {
        k0 = (bf16x8){0, 0, 0, 0, 0, 0, 0, 0};
        k1 = k0;
      }
      *(bf16x8*)&Kl[krow * 72 + kseg * 16] = k0;
      *(bf16x8*)&Kl[krow * 72 + kseg * 16 + 8] = k1;
    }
    {  // stage V transposed: lane=d (coalesced global), write 16 j's per thread
      union { short s[16]; bf16x8 v[2]; } u;
      const unsigned short* vp = qb + (size_t)(j0 + vw4 * 16) * 1536 + 1024 + h * 64 + vd;
#pragma unroll
      for (int m2 = 0; m2 < 16; ++m2) {
        int jg = j0 + vw4 * 16 + m2;
        u.s[m2] = (jg < NSEQ) ? (short)vp[(size_t)m2 * 1536] : (short)0;
      }
      *(bf16x8*)&Vt[vd * 72 + vw4 * 16] = u.v[0];
      *(bf16x8*)&Vt[vd * 72 + vw4 * 16 + 8] = u.v[1];
    }
    __syncthreads();

    f32x4 s4[4];
#pragma unroll
    for (int n = 0; n < 4; ++n) s4[n] = (f32x4){0.f, 0.f, 0.f, 0.f};
#pragma unroll
    for (int c = 0; c < 2; ++c)
#pragma unroll
      for (int n = 0; n < 4; ++n) {
        bf16x8 kf = *(const bf16x8*)&Kl[(n * 16 + r) * 72 + c * 32 + g * 8];
        s4[n] = __builtin_amdgcn_mfma_f32_16x16x32_bf16(qf[c], kf, s4[n], 0, 0, 0);
      }

    float sv[4][4];
#pragma unroll
    for (int reg = 0; reg < 4; ++reg) {
      int ig = i0 + w * 16 + g * 4 + reg;
      const float* bp = (ig < NSEQ) ? (bias + ((size_t)b * NSEQ + ig) * NSEQ) : nullptr;
#pragma unroll
      for (int n = 0; n < 4; ++n) {
        int jc = j0 + n * 16 + r;
        float v = s4[n][reg] * 0.125f;
        if (jc < NSEQ) {
          if (bp) v += bp[jc];
        } else {
          v = -1e30f;
        }
        sv[reg][n] = v;
      }
    }
#pragma unroll
    for (int reg = 0; reg < 4; ++reg) {
      float mt = fmaxf(fmaxf(sv[reg][0], sv[reg][1]), fmaxf(sv[reg][2], sv[reg][3]));
#pragma unroll
      for (int off = 1; off < 16; off <<= 1) mt = fmaxf(mt, __shfl_xor(mt, off, 64));
      float mnew = fmaxf(m_r[reg], mt);
      float fct = __expf(m_r[reg] - mnew);
      float ls = 0.f;
#pragma unroll
      for (int n = 0; n < 4; ++n) {
        float p = __expf(sv[reg][n] - mnew);
        sv[reg][n] = p;
        ls += p;
      }
#pragma unroll
      for (int off = 1; off < 16; off <<= 1) ls += __shfl_xor(ls, off, 64);
      l_r[reg] = l_r[reg] * fct + ls;
      m_r[reg] = mnew;
#pragma unroll
      for (int n = 0; n < 4; ++n) o4[n][reg] *= fct;
    }
#pragma unroll
    for (int reg = 0; reg < 4; ++reg)
#pragma unroll
      for (int n = 0; n < 4; ++n)
        Pl[w][(g * 4 + reg) * 72 + n * 16 + r] = (short)f2bf(sv[reg][n]);

#pragma unroll
    for (int c = 0; c < 2; ++c) {
      bf16x8 pf = *(const bf16x8*)&Pl[w][r * 72 + c * 32 + g * 8];
#pragma unroll
      for (int n = 0; n < 4; ++n) {
        bf16x8 vf = *(const bf16x8*)&Vt[(n * 16 + r) * 72 + c * 32 + g * 8];
        o4[n] = __builtin_amdgcn_mfma_f32_16x16x32_bf16(pf, vf, o4[n], 0, 0, 0);
      }
    }
  }
#pragma unroll
  for (int reg = 0; reg < 4; ++reg) {
    int ig = i0 + w * 16 + g * 4 + reg;
    if (ig >= NSEQ) continue;
    float inv = 1.f / l_r[reg];
    float* op = o + ((size_t)b * NSEQ + ig) * DM + h * 64;
#pragma unroll
    for (int n = 0; n < 4; ++n) op[n * 16 + r] = o4[n][reg] * inv;
  }
}

// ---------------- head -------------------------------------------------------
__global__ __launch_bounds__(256) void head_k(const float* __restrict__ x0,
                                              const float* __restrict__ head_w,
                                              const float* __restrict__ head_b,
                                              float* __restrict__ outp) {
  __shared__ float xs[512];
  int b = blockIdx.y;
  for (int c = threadIdx.x; c < 512; c += 256) xs[c] = x0[b * 512 + c];
  __syncthreads();
  int j = blockIdx.x * 256 + threadIdx.x;
  if (j >= 4273) return;
  float acc = head_b[j];
  for (int k = 0; k < 512; ++k) acc = fmaf(xs[k], head_w[(size_t)k * 4273 + j], acc);
  outp[(size_t)b * 4273 + j] = acc;
}

extern "C" void kernel_launch(void* const* d_in, const int* in_sizes, int n_in,
                              void* d_out, int out_size, void* d_ws, size_t ws_size,
                              hipStream_t stream) {
  const float* seq_embed = (const float*)d_in[0];
  const float* pae = (const float*)d_in[1];
  const float* plddt = (const float*)d_in[2];
  const float* centroid = (const float*)d_in[3];
  const float* orientv = (const float*)d_in[4];
  const float* scv = (const float*)d_in[5];
  const float* eucl = (const float*)d_in[6];
  const float* edgev = (const float*)d_in[7];
  const float* input_proj_w = (const float*)d_in[8];
  const float* input_proj_b = (const float*)d_in[9];
  const float* plddt_w = (const float*)d_in[10];
  const float* plddt_b = (const float*)d_in[11];
  const float* cent_w = (const float*)d_in[12];
  const float* cent_b = (const float*)d_in[13];
  const float* orient_w = (const float*)d_in[14];
  const float* orient_b = (const float*)d_in[15];
  const float* sc_w = (const float*)d_in[16];
  const float* sc_b = (const float*)d_in[17];
  const float* fusion_w = (const float*)d_in[18];
  const float* fusion_b = (const float*)d_in[19];
  const float* pair_w = (const float*)d_in[20];
  const float* pair_b = (const float*)d_in[21];
  const float* pos_enc = (const float*)d_in[22];
  const float* cls_token = (const float*)d_in[23];
  const float* rel_emb = (const float*)d_in[24];
  const float* ln1_g = (const float*)d_in[25];
  const float* ln1_b = (const float*)d_in[26];
  const float* ln2_g = (const float*)d_in[27];
  const float* ln2_b = (const float*)d_in[28];
  const float* in_proj_w = (const float*)d_in[29];
  const float* in_proj_b = (const float*)d_in[30];
  const float* out_proj_w = (const float*)d_in[31];
  const float* out_proj_b = (const float*)d_in[32];
  const float* ff1_w = (const float*)d_in[33];
  const float* ff1_b = (const float*)d_in[34];
  const float* ff2_w = (const float*)d_in[35];
  const float* ff2_b = (const float*)d_in[36];
  const float* norm_g = (const float*)d_in[37];
  const float* norm_b = (const float*)d_in[38];
  const float* head_w = (const float*)d_in[39];
  const float* head_b = (const float*)d_in[40];
  float* outp = (float*)d_out;

  char* ws = (char*)d_ws;
  size_t off = 0;
  auto alloc = [&](size_t bytes) -> void* {
    void* p = (void*)(ws + off);
    off = (off + bytes + 255) & ~(size_t)255;
    return p;
  };
  float* Wc = (float*)alloc((size_t)2560 * 512 * 4);
  float* vecb = (float*)alloc(5632 * 4);
  float* rel = (float*)alloc(2049 * 4);
  float* x = (float*)alloc((size_t)BATCH * NSEQ * DM * 4);
  float* biasb = (float*)alloc((size_t)BATCH * NSEQ * NSEQ * 4);
  unsigned short* z16 = (unsigned short*)alloc((size_t)4100 * 512 * 2);
  unsigned short* qkvb16 = (unsigned short*)alloc((size_t)BATCH * NSEQ * 1536 * 2);
  float* attb = (float*)alloc((size_t)BATCH * NSEQ * DM * 4);
  unsigned short* hbuf16 = (unsigned short*)alloc((size_t)4100 * 1024 * 2);
  unsigned short* wt = (unsigned short*)alloc((size_t)2097152 * 2);
  float* x0 = (float*)alloc(4 * 512 * 4);
  (void)ws_size; (void)in_sizes; (void)n_in; (void)out_size;

  relbias_k<<<9, 256, 0, stream>>>(rel_emb, rel);
  prepvec_k<<<2, 256, 0, stream>>>(plddt_w, plddt_b, cent_w, cent_b, orient_w, orient_b,
                                   sc_w, sc_b, input_proj_b, fusion_w, fusion_b, cls_token,
                                   vecb, x);
  gemm_k<0><<<dim3(8, 40), 256, 0, stream>>>(input_proj_w, fusion_w, nullptr, nullptr, Wc,
                                             2560, 512, 512);
  gemm_embed_k<<<dim3(8, 64), 256, 0, stream>>>(seq_embed, Wc, vecb, plddt, centroid, orientv,
                                                scv, pos_enc, x);
  pairbias_k<<<BATCH * NSEQ, 256, 0, stream>>>(eucl, pae, edgev, pair_w, pair_b, rel, biasb);

  for (int l = 0; l < 6; ++l) {
    wconv_k<<<dim3(16, 24, 4), 256, 0, stream>>>(in_proj_w, out_proj_w, ff1_w, ff2_w, wt, l);
    ln_k<true><<<4100, 64, 0, stream>>>(x, z16, ln1_g + l * 512, ln1_b + l * 512, 4100, 512, 512);
    gemm_bf_k<3, false><<<dim3(12, 33), 256, 0, stream>>>(z16, wt, in_proj_b + (size_t)l * 1536,
                                                          nullptr, qkvb16, 4100, 1536, 512);
    attn_k<<<dim3(17, 8, 4), 256, 0, stream>>>(qkvb16, biasb, attb);
    gemm_bf_k<2, true><<<dim3(4, 33), 256, 0, stream>>>(attb, wt + 786432,
                                                        out_proj_b + (size_t)l * 512, x, x,
                                                        4100, 512, 512);
    ln_k<true><<<4100, 64, 0, stream>>>(x, z16, ln2_g + l * 512, ln2_b + l * 512, 4100, 512, 512);
    gemm_bf_k<1, false><<<dim3(8, 33), 256, 0, stream>>>(z16, wt + 1048576,
                                                         ff1_b + (size_t)l * 1024, nullptr,
                                                         hbuf16, 4100, 1024, 512);
    gemm_bf_k<2, false><<<dim3(4, 33), 256, 0, stream>>>(hbuf16, wt + 1572864,
                                                         ff2_b + (size_t)l * 512, x, x,
                                                         4100, 512, 1024);
  }
  ln_k<false><<<4, 64, 0, stream>>>(x, x0, norm_g, norm_b, 4, NSEQ * DM, 512);
  head_k<<<dim3(17, 4), 256, 0, stream>>>(x0, head_w, head_b, outp);
}